// Round 1
// 274.286 us; speedup vs baseline: 1.0576x; 1.0576x over previous
//
#include <hip/hip_runtime.h>

#define NN 50000
#define NE 600000
#define DD 128
#define NPAD 50048   // 782 * 64
#define SCAN_BLOCKS 49  // ceil(50000/1024)

typedef __attribute__((ext_vector_type(8))) short bf16x8;
typedef __attribute__((ext_vector_type(4))) float f32x4;

__device__ __forceinline__ float bf2f(unsigned int u16) {
    union { unsigned int i; float f; } v; v.i = u16 << 16; return v.f;
}
__device__ __forceinline__ unsigned short f2bf(float f) {
    union { float f; unsigned int i; } v; v.f = f;
    unsigned int i = v.i + 0x7FFFu + ((v.i >> 16) & 1u);
    return (unsigned short)(i >> 16);
}
__device__ __forceinline__ float wred64(float v) {
    #pragma unroll
    for (int o = 32; o; o >>= 1) v += __shfl_xor(v, o, 64);
    return v;
}
__device__ __forceinline__ int tame16(unsigned int u) {
    int e = (int)((u >> 7) & 0xFF);
    return (e >= 100 && e <= 133) ? 1 : 0;
}

// flags[0]=edges int64, flags[1]=x bf16, flags[2]=W bf16, flags[3]=noise bf16
__global__ void probe_k(const int* __restrict__ ei,
                        const unsigned int* __restrict__ xw,
                        const unsigned int* __restrict__ w1w,
                        const unsigned int* __restrict__ nzw,
                        int* __restrict__ flags) {
    const int lane = threadIdx.x;  // 64 threads, 1 block
    int nz = 0;
    #pragma unroll
    for (int i = 0; i < 4; ++i) nz |= ei[2 * (lane * 4 + i) + 1];
    int tx = tame16(xw[lane] & 0xFFFFu);
    int tw = tame16(w1w[lane] & 0xFFFFu);
    int tn = tame16(nzw[lane] & 0xFFFFu);
    #pragma unroll
    for (int o = 32; o; o >>= 1) {
        nz |= __shfl_xor(nz, o, 64);
        tx += __shfl_xor(tx, o, 64);
        tw += __shfl_xor(tw, o, 64);
        tn += __shfl_xor(tn, o, 64);
    }
    if (lane == 0) {
        flags[0] = (nz == 0) ? 1 : 0;
        flags[1] = (tx >= 48) ? 1 : 0;
        flags[2] = (tw >= 48) ? 1 : 0;
        flags[3] = (tn >= 48) ? 1 : 0;
    }
}

__global__ __launch_bounds__(256) void convert_k(
    const void* __restrict__ W1, const void* __restrict__ b1,
    const void* __restrict__ W2, const void* __restrict__ b2,
    const int* __restrict__ flags,
    unsigned short* __restrict__ W1b, unsigned short* __restrict__ b1b,
    unsigned short* __restrict__ W2b, unsigned short* __restrict__ b2b) {
    const int i = blockIdx.x * blockDim.x + threadIdx.x;
    if (i >= DD * DD) return;
    if (flags[2]) {
        W1b[i] = ((const unsigned short*)W1)[i];
        W2b[i] = ((const unsigned short*)W2)[i];
        if (i < DD) { b1b[i] = ((const unsigned short*)b1)[i];
                      b2b[i] = ((const unsigned short*)b2)[i]; }
    } else {
        W1b[i] = f2bf(((const float*)W1)[i]);
        W2b[i] = f2bf(((const float*)W2)[i]);
        if (i < DD) { b1b[i] = f2bf(((const float*)b1)[i]);
                      b2b[i] = f2bf(((const float*)b2)[i]); }
    }
}

// ---- CSR build ----
__global__ __launch_bounds__(256) void hist_k(
    const int* __restrict__ ei, const int* __restrict__ flags,
    int* __restrict__ deg) {
    const int e = blockIdx.x * blockDim.x + threadIdx.x;
    if (e >= NE) return;
    const int d = flags[0] ? (int)((const long long*)ei)[NE + e] : ei[NE + e];
    atomicAdd(&deg[d], 1);
}

__global__ __launch_bounds__(1024) void scan1_k(
    const int* __restrict__ deg, int* __restrict__ offs,
    int* __restrict__ bsum) {
    __shared__ int wsum[16];
    __shared__ int wbase[16];
    __shared__ int tot_s;
    const int tid = threadIdx.x, lane = tid & 63, wv = tid >> 6;
    const int i = blockIdx.x * 1024 + tid;
    const int v = (i < NN) ? deg[i] : 0;
    int incl = v;
    #pragma unroll
    for (int off = 1; off < 64; off <<= 1) {
        int t = __shfl_up(incl, off, 64);
        if (lane >= off) incl += t;
    }
    if (lane == 63) wsum[wv] = incl;
    __syncthreads();
    if (wv == 0 && lane < 16) {
        const int wv_v = wsum[lane];
        int wincl = wv_v;
        #pragma unroll
        for (int off = 1; off < 16; off <<= 1) {
            int t = __shfl_up(wincl, off, 64);
            if (lane >= off) wincl += t;
        }
        wbase[lane] = wincl - wv_v;
        if (lane == 15) tot_s = wincl;
    }
    __syncthreads();
    if (i < NN) offs[i] = wbase[wv] + incl - v;
    if (tid == 0) bsum[blockIdx.x] = tot_s;
}

__global__ __launch_bounds__(1024) void scan2_k(
    int* __restrict__ offs, int* __restrict__ cursor,
    const int* __restrict__ bsum) {
    __shared__ int base_s;
    const int tid = threadIdx.x;
    if (tid < 64) {
        const int v = (tid < SCAN_BLOCKS) ? bsum[tid] : 0;
        int incl = v;
        #pragma unroll
        for (int off = 1; off < 64; off <<= 1) {
            int t = __shfl_up(incl, off, 64);
            if (tid >= off) incl += t;
        }
        if (tid == blockIdx.x) base_s = incl - v;
    }
    __syncthreads();
    const int i = blockIdx.x * 1024 + tid;
    if (i < NN) {
        const int o = offs[i] + base_s;
        offs[i] = o;
        cursor[i] = o;
    }
    if (blockIdx.x == 0 && tid == 0) offs[NN] = NE;
}

__global__ __launch_bounds__(256) void fill_k(
    const int* __restrict__ ei, const int* __restrict__ flags,
    int* __restrict__ cursor, int* __restrict__ eidx) {
    const int e = blockIdx.x * blockDim.x + threadIdx.x;
    if (e >= NE) return;
    int s, d;
    if (flags[0]) {
        const long long* e64 = (const long long*)ei;
        s = (int)e64[e]; d = (int)e64[NE + e];
    } else {
        s = ei[e]; d = ei[NE + e];
    }
    const int pos = atomicAdd(&cursor[d], 1);
    eidx[pos] = s;
}

// One wave/row: featu (packed bf16, in d_out) = clip(x).
// Row NN is written as an all-zero row (gather padding target for agg_k).
__global__ __launch_bounds__(256) void prep_k(
    const void* __restrict__ x, const int* __restrict__ flags,
    unsigned int* __restrict__ featu) {
    const int row = (blockIdx.x * blockDim.x + threadIdx.x) >> 6;
    const int lane = threadIdx.x & 63;
    if (row > NN) return;
    if (row == NN) { featu[(size_t)NN * 64 + lane] = 0u; return; }
    float v0, v1;
    if (flags[1]) {
        const unsigned int px = ((const unsigned int*)x)[(size_t)row * 64 + lane];
        v0 = bf2f(px & 0xFFFFu); v1 = bf2f(px >> 16);
    } else {
        const float2 px = ((const float2*)x)[(size_t)row * 64 + lane];
        v0 = px.x; v1 = px.y;
    }
    const float ss = wred64(v0 * v0 + v1 * v1);
    const float nrm = sqrtf(ss);
    const float sc = nrm > 1.0f ? 1.0f / nrm : 1.0f;
    featu[(size_t)row * 64 + lane] =
        (unsigned int)f2bf(v0 * sc) | ((unsigned int)f2bf(v1 * sc) << 16);
}

// One wave/node: aggu[n] = pack_bf16( feat[n] + noise[n] + sum feat[src] ).
// v2: index-in-register + shfl broadcast; lanes 0-31 gather even edges, lanes
// 32-63 gather odd edges (uint2 = 8B/lane -> 2 neighbor rows per load instr).
// Degree padded to a multiple of 16 edges via the zero row at index NN:
// no tail loop, no predication, all loads of a batch issued before any wait.
__global__ __launch_bounds__(256) void agg_k(
    const int* __restrict__ offs, const int* __restrict__ eidx,
    const uint2* __restrict__ featu2, const void* __restrict__ noise,
    const int* __restrict__ flags, uint2* __restrict__ aggu2) {
    const int node = (blockIdx.x * blockDim.x + threadIdx.x) >> 6;
    const int lane = threadIdx.x & 63;
    if (node >= NN) return;
    const int c = lane & 31;
    const int h = lane >> 5;

    // lanes 0-31: self term; lanes 32-63: noise term (independent loads,
    // exec-masked, both in flight before first use)
    float a0, a1, a2, a3;
    if (h == 0) {
        const uint2 s = featu2[(size_t)node * 32 + c];
        a0 = bf2f(s.x & 0xFFFFu); a1 = bf2f(s.x >> 16);
        a2 = bf2f(s.y & 0xFFFFu); a3 = bf2f(s.y >> 16);
    } else {
        if (flags[3]) {
            const uint2 n = ((const uint2*)noise)[(size_t)node * 32 + c];
            a0 = bf2f(n.x & 0xFFFFu); a1 = bf2f(n.x >> 16);
            a2 = bf2f(n.y & 0xFFFFu); a3 = bf2f(n.y >> 16);
        } else {
            const float4 n = ((const float4*)noise)[(size_t)node * 32 + c];
            a0 = n.x; a1 = n.y; a2 = n.z; a3 = n.w;
        }
    }

    const int e0 = offs[node];
    const int cnt = offs[node + 1] - e0;
    for (int base = 0; base < cnt; base += 64) {
        const int rem = cnt - base;
        // one coalesced load: up to 64 edge indices, OOB lanes -> zero row NN
        int myi = NN;
        if (lane < rem) myi = eidx[e0 + base + lane];
        const int pairs = (rem < 64 ? rem + 1 : 64) >> 1;
        const int pb = (pairs + 7) & ~7;   // round up to 8 pairs (16 edges)
        for (int p = 0; p < pb; p += 8) {
            uint2 u[8];
            #pragma unroll
            for (int q = 0; q < 8; ++q) {
                const int s = __shfl(myi, 2 * (p + q) + h, 64);
                u[q] = featu2[(size_t)s * 32 + c];
            }
            #pragma unroll
            for (int q = 0; q < 8; ++q) {
                a0 += bf2f(u[q].x & 0xFFFFu); a1 += bf2f(u[q].x >> 16);
                a2 += bf2f(u[q].y & 0xFFFFu); a3 += bf2f(u[q].y >> 16);
            }
        }
    }

    // combine even-edge half (lanes 0-31) with odd-edge half (lanes 32-63)
    a0 += __shfl_xor(a0, 32, 64);
    a1 += __shfl_xor(a1, 32, 64);
    a2 += __shfl_xor(a2, 32, 64);
    a3 += __shfl_xor(a3, 32, 64);

    if (h == 0) {
        uint2 o;
        o.x = (unsigned int)f2bf(a0) | ((unsigned int)f2bf(a1) << 16);
        o.y = (unsigned int)f2bf(a2) | ((unsigned int)f2bf(a3) << 16);
        aggu2[(size_t)node * 32 + c] = o;
    }
}

// MFMA GEMM: C[r][j] = sum_k agg[r][k] * W[j][k] + b[j].
template<bool LAYER1>
__global__ __launch_bounds__(256) void gemm_k(
    const unsigned short* __restrict__ aggb,   // NPAD x 128 bf16
    const unsigned short* __restrict__ Wb,     // 128 x 128 bf16 (row-major)
    const unsigned short* __restrict__ bb,     // 128 bf16
    unsigned short* __restrict__ featb,        // LAYER1 output
    float* __restrict__ outf) {                // LAYER2 output
    __shared__ unsigned short Wl[128 * 136];   // +8 pad: kills quad bank conflict
    __shared__ unsigned short bl[128];
    const int t = threadIdx.x;
    #pragma unroll
    for (int i = 0; i < 8; ++i) {
        const int idx8 = t + i * 256;
        const int base = idx8 * 8;
        const int row = base >> 7, col = base & 127;
        *(uint4*)&Wl[row * 136 + col] = ((const uint4*)Wb)[idx8];
    }
    if (t < 128) bl[t] = bb[t];

    const int lane = t & 63;
    const int w = t >> 6;
    const int n15 = lane & 15;
    const int quad = lane >> 4;
    const int rbase = blockIdx.x * 64 + w * 16;

    bf16x8 af[4];
    #pragma unroll
    for (int kc = 0; kc < 4; ++kc)
        af[kc] = *(const bf16x8*)&aggb[(size_t)(rbase + n15) * DD + kc * 32 + quad * 8];

    __syncthreads();

    float h[32];
    #pragma unroll
    for (int nt = 0; nt < 8; ++nt) {
        f32x4 acc = {0.f, 0.f, 0.f, 0.f};
        #pragma unroll
        for (int kc = 0; kc < 4; ++kc) {
            const bf16x8 bfr =
                *(const bf16x8*)&Wl[(nt * 16 + n15) * 136 + kc * 32 + quad * 8];
            acc = __builtin_amdgcn_mfma_f32_16x16x32_bf16(af[kc], bfr, acc, 0, 0, 0);
        }
        const float bj = bf2f((unsigned int)bl[nt * 16 + n15]);
        #pragma unroll
        for (int r = 0; r < 4; ++r) h[nt * 4 + r] = acc[r] + bj;
    }

    if (LAYER1) {
        const float S = 1.0507009873554805f, AL = 1.6732632423543772f;
        float ss[4] = {0.f, 0.f, 0.f, 0.f};
        #pragma unroll
        for (int nt = 0; nt < 8; ++nt)
            #pragma unroll
            for (int r = 0; r < 4; ++r) {
                float v = h[nt * 4 + r];
                v = v > 0.f ? S * v : S * AL * expm1f(v);
                h[nt * 4 + r] = v;
                ss[r] += v * v;
            }
        #pragma unroll
        for (int r = 0; r < 4; ++r) {
            #pragma unroll
            for (int off = 1; off < 16; off <<= 1)
                ss[r] += __shfl_xor(ss[r], off, 64);
        }
        float sc[4];
        #pragma unroll
        for (int r = 0; r < 4; ++r) {
            const float nr = sqrtf(ss[r]);
            sc[r] = nr > 1.f ? 1.f / nr : 1.f;
        }
        #pragma unroll
        for (int r = 0; r < 4; ++r) {
            const int row = rbase + quad * 4 + r;
            if (row < NN) {
                #pragma unroll
                for (int nt = 0; nt < 8; ++nt)
                    featb[(size_t)row * DD + nt * 16 + n15] =
                        f2bf(h[nt * 4 + r] * sc[r]);
            }
        }
    } else {
        #pragma unroll
        for (int r = 0; r < 4; ++r) {
            const int row = rbase + quad * 4 + r;
            if (row < NN) {
                #pragma unroll
                for (int nt = 0; nt < 8; ++nt)
                    outf[(size_t)row * DD + nt * 16 + n15] = h[nt * 4 + r];
            }
        }
    }
}

extern "C" void kernel_launch(void* const* d_in, const int* in_sizes, int n_in,
                              void* d_out, int out_size, void* d_ws, size_t ws_size,
                              hipStream_t stream) {
    const void* x  = d_in[0];
    const int*  ei = (const int*)d_in[1];
    const void* W1 = d_in[2];
    const void* b1 = d_in[3];
    const void* W2 = d_in[4];
    const void* b2 = d_in[5];
    const void* n1 = d_in[6];
    const void* n2 = d_in[7];

    // ws layout (~15.9 MB)
    unsigned short* aggb = (unsigned short*)d_ws;        // NPAD*128 bf16
    unsigned short* W1b  = aggb + (size_t)NPAD * DD;
    unsigned short* b1b  = W1b + DD * DD;
    unsigned short* W2b  = b1b + DD;
    unsigned short* b2b  = W2b + DD * DD;
    int* flags  = (int*)(b2b + DD);
    int* deg    = flags + 4;
    int* offs   = deg + NN;
    int* cursor = offs + NN + 1;
    int* bsum   = cursor + NN;
    int* eidx   = bsum + 64;
    unsigned int* featu = (unsigned int*)d_out;

    probe_k<<<1, 64, 0, stream>>>(ei, (const unsigned int*)x,
                                  (const unsigned int*)W1,
                                  (const unsigned int*)n1, flags);
    convert_k<<<(DD * DD + 255) / 256, 256, 0, stream>>>(W1, b1, W2, b2, flags,
                                                         W1b, b1b, W2b, b2b);

    // CSR build (edges identical for both layers)
    hipMemsetAsync(deg, 0, NN * sizeof(int), stream);
    hist_k<<<(NE + 255) / 256, 256, 0, stream>>>(ei, flags, deg);
    scan1_k<<<SCAN_BLOCKS, 1024, 0, stream>>>(deg, offs, bsum);
    scan2_k<<<SCAN_BLOCKS, 1024, 0, stream>>>(offs, cursor, bsum);
    fill_k<<<(NE + 255) / 256, 256, 0, stream>>>(ei, flags, cursor, eidx);

    // Layer 1 (prep covers NN+1 rows: row NN = zero padding row)
    prep_k<<<((NN + 1) * 64 + 255) / 256, 256, 0, stream>>>(x, flags, featu);
    agg_k<<<(NN * 64) / 256, 256, 0, stream>>>(offs, eidx, (const uint2*)featu,
                                               n1, flags, (uint2*)aggb);
    gemm_k<true><<<NPAD / 64, 256, 0, stream>>>(aggb, W1b, b1b,
                                                (unsigned short*)featu, nullptr);

    // Layer 2 (featu/d_out holds hc bf16; row NN still zero from prep)
    agg_k<<<(NN * 64) / 256, 256, 0, stream>>>(offs, eidx, (const uint2*)featu,
                                               n2, flags, (uint2*)aggb);
    gemm_k<false><<<NPAD / 64, 256, 0, stream>>>(aggb, W2b, b2b, nullptr,
                                                 (float*)d_out);
}